// Round 19
// baseline (141.811 us; speedup 1.0000x reference)
//
#include <hip/hip_runtime.h>
#include <hip/hip_bf16.h>

// AttentionHead: B=4, T=2048, C=1024, hs=64. All fp32 in/out.
#define D_MODEL 1024
#define HS 64
#define T_LEN 2048
#define JCH 256          // j-chunk width per attention block
#define NCH 8            // max chunks per row = T_LEN/JCH

typedef __attribute__((ext_vector_type(8))) short bf16x8;   // MFMA A/B frag
typedef __attribute__((ext_vector_type(4))) float f32x4;    // MFMA C/D frag

// split 8 floats into hi/lo bf16 (truncation split: residual exact)
__device__ inline void split8(const float* v, int4& hi, int4& lo) {
    union { unsigned short u[8]; int4 v4; } uh, ul;
    #pragma unroll
    for (int i = 0; i < 8; ++i) {
        const unsigned int b = __float_as_uint(v[i]);
        const unsigned short h = (unsigned short)(b >> 16);
        const float r = v[i] - __uint_as_float((unsigned int)h << 16);
        uh.u[i] = h;
        ul.u[i] = (unsigned short)(__float_as_uint(r) >> 16);
    }
    hi = uh.v4; lo = ul.v4;
}

// fp32 -> bf16 round-to-nearest-even (finite inputs only here)
__device__ inline unsigned short f2bf_rne(float f) {
    const unsigned int b = __float_as_uint(f);
    return (unsigned short)((b + 0x7FFFu + ((b >> 16) & 1u)) >> 16);
}
__device__ inline float bf2f(unsigned short h) {
    return __uint_as_float((unsigned int)h << 16);
}

// async 16B global -> LDS (direct-to-shared DMA). LDS dest is wave-uniform
// base; HW writes ldsbase + lane*16. gptr is per-lane.
__device__ inline void async_copy16(const short* g, short* l) {
    __builtin_amdgcn_global_load_lds(
        (const __attribute__((address_space(1))) void*)g,
        (__attribute__((address_space(3))) void*)l, 16, 0, 0);
}

// ---------------------------------------------------------------------------
// Kernel 0: prep — pre-split x and W into FRAGMENT-ORDERED bf16 hi/lo.
// (UNCHANGED — passing.)
// ---------------------------------------------------------------------------
__global__ __launch_bounds__(256) void prep_kernel(
    const float* __restrict__ x,
    const float* __restrict__ Wq, const float* __restrict__ Wk,
    const float* __restrict__ Wv,
    short* __restrict__ xh, short* __restrict__ xl,
    short* __restrict__ wh, short* __restrict__ wl, int BT)
{
    __shared__ float tile[64][69];
    const int tid = threadIdx.x;
    const int bx  = blockIdx.x;
    const int nxb = BT >> 4;

    if (bx < nxb) {
        const int mtg = bx;
        #pragma unroll
        for (int i = 0; i < 8; ++i) {
            const int s    = tid + 256 * i;
            const int kc   = s >> 6;
            const int lane = s & 63;
            const float* src = x + (size_t)(mtg * 16 + (lane & 15)) * D_MODEL
                                 + kc * 32 + (lane >> 4) * 8;
            float v[8];
            *(float4*)&v[0] = *(const float4*)src;
            *(float4*)&v[4] = *(const float4*)(src + 4);
            int4 hi, lo;
            split8(v, hi, lo);
            const size_t off = ((size_t)(mtg * 32 + kc) * 64 + lane) * 8;
            *(int4*)(xh + off) = hi;
            *(int4*)(xl + off) = lo;
        }
    } else {
        const int wb = bx - nxb;
        const int kb = wb & 15;           // k-block 0..15
        const int m  = wb >> 4;           // matrix 0..2
        const float* W = (m == 0) ? Wq : (m == 1) ? Wk : Wv;
        #pragma unroll
        for (int it = 0; it < 4; ++it) {
            const int idx = tid + 256 * it;
            const int kr = idx >> 4, c4 = idx & 15;
            *(float4*)&tile[kr][4 * c4] =
                *(const float4*)(W + (size_t)(kb * 64 + kr) * HS + 4 * c4);
        }
        __syncthreads();
        #pragma unroll
        for (int i = 0; i < 2; ++i) {
            const int s    = tid + 256 * i;    // 0..511
            const int ntl  = s >> 7;           // 0..3
            const int kcl  = (s >> 6) & 1;
            const int lane = s & 63;
            const int n    = ntl * 16 + (lane & 15);
            const int krel = kcl * 32 + (lane >> 4) * 8;
            float v[8];
            #pragma unroll
            for (int e = 0; e < 8; ++e) v[e] = tile[krel + e][n];
            int4 hi, lo;
            split8(v, hi, lo);
            const size_t off =
                ((size_t)((m * 4 + ntl) * 32 + kb * 2 + kcl) * 64 + lane) * 8;
            *(int4*)(wh + off) = hi;
            *(int4*)(wl + off) = lo;
        }
    }
}

// ---------------------------------------------------------------------------
// Kernel 1: QKV projection (async staging; fragment-ordered outputs).
// Grid SWAPPED to (3, BT/32): the three nb column-slices sharing one 32-row
// x-fragment range are now consecutive in dispatch order -> co-resident ->
// x-frag re-reads hit L2/L3 while hot (was: full pass apart). Bit-identical.
// ---------------------------------------------------------------------------
__global__ __launch_bounds__(256) void qkv_kernel(
    const short* __restrict__ xh, const short* __restrict__ xl,
    const short* __restrict__ wh, const short* __restrict__ wl,
    const float* __restrict__ bq, const float* __restrict__ bk,
    short* __restrict__ qfh, short* __restrict__ qfl,
    short* __restrict__ kfh, short* __restrict__ kfl, short* __restrict__ vf,
    int BT)
{
    __shared__ __align__(16) short A_lds[8 * 512];
    __shared__ __align__(16) short B_lds[16 * 512];

    const int tid  = threadIdx.x;
    const int r0   = blockIdx.y * 32;     // row tile (slow dim)
    const int nb   = blockIdx.x;          // col slice 0..2 (fast dim)
    const int wave = tid >> 6;
    const int lane = tid & 63;
    const int mt_w = wave >> 1;
    const int nt0  = (wave & 1) * 2;

    f32x4 acc0 = (f32x4)(0.f);
    f32x4 acc1 = (f32x4)(0.f);

    const size_t mtg0 = (size_t)(r0 >> 4);
    const size_t ntg0 = (size_t)(nb * 4);

    for (int k0 = 0; k0 < D_MODEL; k0 += 64) {
        const int kc0 = k0 >> 5;
        __syncthreads();
        #pragma unroll
        for (int ii = 0; ii < 6; ++ii) {
            const int g = wave * 6 + ii;
            if (g < 8) {
                const int mt = g >> 2, kcl = (g >> 1) & 1, p = g & 1;
                const short* base = p ? xl : xh;
                const short* gsrc = base + ((mtg0 + mt) * 32 + kc0 + kcl) * 512;
                async_copy16(gsrc + lane * 8, &A_lds[g * 512]);
            } else {
                const int gb = g - 8;
                const int nt = gb >> 2, kcl = (gb >> 1) & 1, p = gb & 1;
                const short* base = p ? wl : wh;
                const short* gsrc = base + ((ntg0 + nt) * 32 + kc0 + kcl) * 512;
                async_copy16(gsrc + lane * 8, &B_lds[gb * 512]);
            }
        }
        __syncthreads();
        #pragma unroll
        for (int kcl = 0; kcl < 2; ++kcl) {
            const bf16x8 afh = *(const bf16x8*)&A_lds[(mt_w * 4 + kcl * 2 + 0) * 512 + lane * 8];
            const bf16x8 afl = *(const bf16x8*)&A_lds[(mt_w * 4 + kcl * 2 + 1) * 512 + lane * 8];
            {
                const bf16x8 bfh = *(const bf16x8*)&B_lds[(nt0 * 4 + kcl * 2 + 0) * 512 + lane * 8];
                const bf16x8 bfl = *(const bf16x8*)&B_lds[(nt0 * 4 + kcl * 2 + 1) * 512 + lane * 8];
                acc0 = __builtin_amdgcn_mfma_f32_16x16x32_bf16(afh, bfh, acc0, 0, 0, 0);
                acc0 = __builtin_amdgcn_mfma_f32_16x16x32_bf16(afh, bfl, acc0, 0, 0, 0);
                acc0 = __builtin_amdgcn_mfma_f32_16x16x32_bf16(afl, bfh, acc0, 0, 0, 0);
            }
            {
                const bf16x8 bfh = *(const bf16x8*)&B_lds[((nt0 + 1) * 4 + kcl * 2 + 0) * 512 + lane * 8];
                const bf16x8 bfl = *(const bf16x8*)&B_lds[((nt0 + 1) * 4 + kcl * 2 + 1) * 512 + lane * 8];
                acc1 = __builtin_amdgcn_mfma_f32_16x16x32_bf16(afh, bfh, acc1, 0, 0, 0);
                acc1 = __builtin_amdgcn_mfma_f32_16x16x32_bf16(afh, bfl, acc1, 0, 0, 0);
                acc1 = __builtin_amdgcn_mfma_f32_16x16x32_bf16(afl, bfh, acc1, 0, 0, 0);
            }
        }
    }

    // ---- epilogue: C/D layout col=lane&15, row=(lane>>4)*4+reg
    const int rowb = r0 + mt_w * 16 + (lane >> 4) * 4;
    #pragma unroll
    for (int j = 0; j < 2; ++j) {
        const f32x4 a = (j == 0) ? acc0 : acc1;
        const int c = nb * 64 + (nt0 + j) * 16 + (lane & 15);
        if (c < 128) {
            // q/k -> fragment-ordered split bf16
            const int cc    = (c < 64) ? c : (c - 64);
            const float bias = (c < 64) ? bq[cc] : bk[cc];
            short* dsth = (c < 64) ? qfh : kfh;
            short* dstl = (c < 64) ? qfl : kfl;
            const int tile16 = rowb >> 4;
            const int kc2   = cc >> 5;
            const int quadd = (cc & 31) >> 3;
            const int e     = cc & 7;
            #pragma unroll
            for (int r = 0; r < 4; ++r) {
                const float val = a[r] + bias;
                const unsigned int b = __float_as_uint(val);
                const unsigned short h = (unsigned short)(b >> 16);
                const float res = val - __uint_as_float((unsigned int)h << 16);
                const unsigned short l16 = (unsigned short)(__float_as_uint(res) >> 16);
                const int laned = ((rowb + r) & 15) | (quadd << 4);
                const size_t off = ((size_t)((tile16 * 2 + kc2) * 64 + laned)) * 8 + e;
                dsth[off] = (short)h;
                dstl[off] = (short)l16;
            }
        } else {
            // v -> fragment-ordered RNE bf16 (vf); 4 consecutive e -> 8B store
            const int cv    = c - 128;
            const int vb    = rowb >> 6;
            const int jc2   = (rowb & 63) >> 5;
            const int quadd = (rowb & 31) >> 3;
            const int gg    = jc2 * 4 + (cv >> 4);
            const int laned = (cv & 15) | (quadd << 4);
            const size_t base = ((size_t)((vb * 8 + gg) * 64 + laned)) * 8 + (rowb & 7);
            short4 pk;
            pk.x = (short)f2bf_rne(a[0]);
            pk.y = (short)f2bf_rne(a[1]);
            pk.z = (short)f2bf_rne(a[2]);
            pk.w = (short)f2bf_rne(a[3]);
            *(short4*)(vf + base) = pk;
        }
    }
}

// ---------------------------------------------------------------------------
// Kernel 2: flash attention via MFMA, async staging.
// (UNCHANGED — passing.)
// ---------------------------------------------------------------------------
__global__ __launch_bounds__(256) void attn_kernel(
    const short* __restrict__ qfh, const short* __restrict__ qfl,
    const short* __restrict__ kfh, const short* __restrict__ kfl,
    const short* __restrict__ vf, const int* __restrict__ maskp,
    float* __restrict__ part_O, float* __restrict__ part_ml, int BT)
{
    __shared__ __align__(16) short Kh[4096], Kl[4096];
    __shared__ __align__(16) short Vt[4096];
    __shared__ __align__(16) short Pl[4][16 * 72];

    const int tile  = blockIdx.x;
    const int chunk = blockIdx.y;
    const int r0 = tile * 64;
    const int tb = r0 / T_LEN;
    const int t0 = r0 - tb * T_LEN;
    const int mask = (*maskp != 0);
    const int n_max = mask ? (t0 + 64) : T_LEN;
    const int j0 = chunk * JCH;
    if (j0 >= n_max) return;
    const int hi_j = min(j0 + JCH, n_max);
    const int njt = (hi_j - j0 + 63) >> 6;

    const int tid  = threadIdx.x;
    const int w    = tid >> 6;
    const int lane = tid & 63;
    const int quad = lane >> 4;
    const int l15  = lane & 15;
    const int rw0  = t0 + 16 * w;
    const int rowa = r0 + 16 * w + quad * 4;

    // Q fragments: direct 16B loads from fragment-ordered split buffers
    bf16x8 qh[2], ql[2];
    {
        const size_t qt = (size_t)(r0 >> 4) + w;
        #pragma unroll
        for (int kc = 0; kc < 2; ++kc) {
            qh[kc] = *(const bf16x8*)&qfh[((qt * 2 + kc) * 64 + lane) * 8];
            ql[kc] = *(const bf16x8*)&qfl[((qt * 2 + kc) * 64 + lane) * 8];
        }
    }

    f32x4 oacc[4];
    #pragma unroll
    for (int nt = 0; nt < 4; ++nt) oacc[nt] = (f32x4)(0.f);
    float m_r[4] = {-INFINITY, -INFINITY, -INFINITY, -INFINITY};
    float l_r[4] = {0.f, 0.f, 0.f, 0.f};

    for (int jt = 0; jt < njt; ++jt) {
        const int jbase = j0 + jt * 64;
        __syncthreads();
        {
            const size_t kt0 = (size_t)(tb * 128) + (jbase >> 4);
            const size_t vb  = (size_t)(tb * 32) + (jbase >> 6);
            #pragma unroll
            for (int ii = 0; ii < 6; ++ii) {
                const int g = w * 6 + ii;       // 0..23
                if (g < 8) {
                    const short* src = kfh + ((kt0 + (g >> 1)) * 2 + (g & 1)) * 512;
                    async_copy16(src + lane * 8, &Kh[g * 512]);
                } else if (g < 16) {
                    const int gg = g - 8;
                    const short* src = kfl + ((kt0 + (gg >> 1)) * 2 + (gg & 1)) * 512;
                    async_copy16(src + lane * 8, &Kl[gg * 512]);
                } else {
                    const int gg = g - 16;
                    const short* src = vf + (vb * 8 + gg) * 512;
                    async_copy16(src + lane * 8, &Vt[gg * 512]);
                }
            }
        }
        __syncthreads();

        const bool active = (!mask) || (jbase <= rw0 + 15);
        if (active) {
            f32x4 sacc[4];
            #pragma unroll
            for (int jsub = 0; jsub < 4; ++jsub) {
                f32x4 s = (f32x4)(0.f);
                #pragma unroll
                for (int kc = 0; kc < 2; ++kc) {
                    const bf16x8 kh = *(const bf16x8*)&Kh[((jsub * 2 + kc) * 64 + lane) * 8];
                    const bf16x8 kl = *(const bf16x8*)&Kl[((jsub * 2 + kc) * 64 + lane) * 8];
                    s = __builtin_amdgcn_mfma_f32_16x16x32_bf16(qh[kc], kh, s, 0, 0, 0);
                    s = __builtin_amdgcn_mfma_f32_16x16x32_bf16(qh[kc], kl, s, 0, 0, 0);
                    s = __builtin_amdgcn_mfma_f32_16x16x32_bf16(ql[kc], kh, s, 0, 0, 0);
                }
                sacc[jsub] = s;
            }
            float sval[4][4], rmax[4];
            #pragma unroll
            for (int r = 0; r < 4; ++r) rmax[r] = -INFINITY;
            #pragma unroll
            for (int jsub = 0; jsub < 4; ++jsub) {
                const int jg = jbase + jsub * 16 + l15;
                #pragma unroll
                for (int r = 0; r < 4; ++r) {
                    const int tg = rw0 + quad * 4 + r;
                    const float vv = (mask && (jg > tg)) ? -INFINITY : 8.0f * sacc[jsub][r];
                    sval[jsub][r] = vv;
                    rmax[r] = fmaxf(rmax[r], vv);
                }
            }
            #pragma unroll
            for (int d = 1; d < 16; d <<= 1)
                #pragma unroll
                for (int r = 0; r < 4; ++r)
                    rmax[r] = fmaxf(rmax[r], __shfl_xor(rmax[r], d));
            float alpha[4], msafe[4];
            #pragma unroll
            for (int r = 0; r < 4; ++r) {
                const float mn = fmaxf(m_r[r], rmax[r]);
                msafe[r] = (mn == -INFINITY) ? 0.f : mn;
                alpha[r] = __expf(m_r[r] - msafe[r]);
                m_r[r] = mn;
            }
            short* Pw = &Pl[w][0];
            float rsum[4] = {0.f, 0.f, 0.f, 0.f};
            #pragma unroll
            for (int jsub = 0; jsub < 4; ++jsub) {
                #pragma unroll
                for (int r = 0; r < 4; ++r) {
                    const float e = __expf(sval[jsub][r] - msafe[r]);
                    const unsigned short eb = f2bf_rne(e);
                    Pw[(quad * 4 + r) * 72 + jsub * 16 + l15] = (short)eb;
                    rsum[r] += bf2f(eb);
                }
            }
            #pragma unroll
            for (int d = 1; d < 16; d <<= 1)
                #pragma unroll
                for (int r = 0; r < 4; ++r)
                    rsum[r] += __shfl_xor(rsum[r], d);
            #pragma unroll
            for (int r = 0; r < 4; ++r)
                l_r[r] = l_r[r] * alpha[r] + rsum[r];
            #pragma unroll
            for (int nt = 0; nt < 4; ++nt)
                #pragma unroll
                for (int r = 0; r < 4; ++r)
                    oacc[nt][r] *= alpha[r];
            bf16x8 pf[2];
            #pragma unroll
            for (int jc = 0; jc < 2; ++jc)
                pf[jc] = *(const bf16x8*)&Pw[l15 * 72 + jc * 32 + quad * 8];
            #pragma unroll
            for (int nt = 0; nt < 4; ++nt) {
                #pragma unroll
                for (int jc = 0; jc < 2; ++jc) {
                    const bf16x8 vfr = *(const bf16x8*)&Vt[((jc * 4 + nt) * 64 + lane) * 8];
                    oacc[nt] = __builtin_amdgcn_mfma_f32_16x16x32_bf16(pf[jc], vfr, oacc[nt], 0, 0, 0);
                }
            }
        }
    }

    #pragma unroll
    for (int nt = 0; nt < 4; ++nt)
        #pragma unroll
        for (int r = 0; r < 4; ++r)
            part_O[((size_t)(rowa + r) * NCH + chunk) * HS + nt * 16 + l15] = oacc[nt][r];
    if (l15 == 0) {
        #pragma unroll
        for (int r = 0; r < 4; ++r) {
            float2 ml;
            ml.x = m_r[r];
            ml.y = l_r[r];
            *(float2*)(part_ml + ((size_t)(rowa + r) * NCH + chunk) * 2) = ml;
        }
    }
}

// ---------------------------------------------------------------------------
// Kernel 3: combine chunk partials — vectorized (1 thread per row x 4 dims).
// (UNCHANGED — passing, bit-identical math.)
// ---------------------------------------------------------------------------
__global__ __launch_bounds__(256) void combine_kernel(
    const float* __restrict__ part_O, const float* __restrict__ part_ml,
    const int* __restrict__ maskp, float* __restrict__ out)
{
    const int f = blockIdx.x * 256 + threadIdx.x;   // BT*16 threads total
    const int row = f >> 4;
    const int d4 = (f & 15) * 4;
    const int t = row & (T_LEN - 1);
    const int mask = (*maskp != 0);
    const int n = mask ? (t + 1) : T_LEN;
    const int nc = (n + JCH - 1) / JCH;

    const float2* mlp = (const float2*)(part_ml + (size_t)row * NCH * 2);
    float M = -INFINITY;
    for (int c = 0; c < nc; ++c) M = fmaxf(M, mlp[c].x);
    float L = 0.f;
    float Ox = 0.f, Oy = 0.f, Oz = 0.f, Ow = 0.f;
    for (int c = 0; c < nc; ++c) {
        const float2 ml = mlp[c];
        const float w = __expf(ml.x - M);
        L += ml.y * w;
        const float4 p = *(const float4*)(part_O + ((size_t)row * NCH + c) * HS + d4);
        Ox = fmaf(p.x, w, Ox);
        Oy = fmaf(p.y, w, Oy);
        Oz = fmaf(p.z, w, Oz);
        Ow = fmaf(p.w, w, Ow);
    }
    float4 res;
    res.x = Ox / L;
    res.y = Oy / L;
    res.z = Oz / L;
    res.w = Ow / L;
    *(float4*)(out + (size_t)row * HS + d4) = res;
}

// ---------------------------------------------------------------------------
extern "C" void kernel_launch(void* const* d_in, const int* in_sizes, int n_in,
                              void* d_out, int out_size, void* d_ws, size_t ws_size,
                              hipStream_t stream) {
    const float* x  = (const float*)d_in[0];
    const float* Wq = (const float*)d_in[1];
    const float* bq = (const float*)d_in[2];
    const float* Wk = (const float*)d_in[3];
    const float* bk = (const float*)d_in[4];
    const float* Wv = (const float*)d_in[5];
    const int* maskp = (const int*)d_in[6];

    const int BT = in_sizes[0] / D_MODEL;   // 8192

    // ws layout: floats pO [BT*NCH*64], pml [BT*NCH*2]; shorts xh,xl
    // [BT*1024], wh,wl [192*1024], qfh,qfl,kfh,kfl,vf [BT*64].
    float* pO  = (float*)d_ws;
    float* pml = pO + (size_t)BT * NCH * HS;
    short* xh  = (short*)(pml + (size_t)BT * NCH * 2);
    short* xl  = xh + (size_t)BT * D_MODEL;
    short* wh  = xl + (size_t)BT * D_MODEL;
    short* wl  = wh + (size_t)192 * D_MODEL;
    short* qfh = wl + (size_t)192 * D_MODEL;
    short* qfl = qfh + (size_t)BT * HS;
    short* kfh = qfl + (size_t)BT * HS;
    short* kfl = kfh + (size_t)BT * HS;
    short* vf  = kfl + (size_t)BT * HS;

    prep_kernel<<<BT / 16 + 48, 256, 0, stream>>>(x, Wq, Wk, Wv, xh, xl, wh, wl, BT);
    dim3 qgrid(3, BT / 32);
    qkv_kernel<<<qgrid, 256, 0, stream>>>(xh, xl, wh, wl, bq, bk,
                                          qfh, qfl, kfh, kfl, vf, BT);
    dim3 agrid(BT / 64, NCH);
    attn_kernel<<<agrid, 256, 0, stream>>>(qfh, qfl, kfh, kfl, vf, maskp,
                                           pO, pml, BT);
    combine_kernel<<<(BT * 16) / 256, 256, 0, stream>>>(pO, pml, maskp, (float*)d_out);
}

// Round 20
// 136.254 us; speedup vs baseline: 1.0408x; 1.0408x over previous
//
#include <hip/hip_runtime.h>
#include <hip/hip_bf16.h>

// AttentionHead: B=4, T=2048, C=1024, hs=64. All fp32 in/out.
#define D_MODEL 1024
#define HS 64
#define T_LEN 2048
#define JCH 256          // j-chunk width per attention block
#define NCH 8            // max chunks per row = T_LEN/JCH

typedef __attribute__((ext_vector_type(8))) short bf16x8;   // MFMA A/B frag
typedef __attribute__((ext_vector_type(4))) float f32x4;    // MFMA C/D frag

// split 8 floats into hi/lo bf16 (truncation split: residual exact)
__device__ inline void split8(const float* v, int4& hi, int4& lo) {
    union { unsigned short u[8]; int4 v4; } uh, ul;
    #pragma unroll
    for (int i = 0; i < 8; ++i) {
        const unsigned int b = __float_as_uint(v[i]);
        const unsigned short h = (unsigned short)(b >> 16);
        const float r = v[i] - __uint_as_float((unsigned int)h << 16);
        uh.u[i] = h;
        ul.u[i] = (unsigned short)(__float_as_uint(r) >> 16);
    }
    hi = uh.v4; lo = ul.v4;
}

// fp32 -> bf16 round-to-nearest-even (finite inputs only here)
__device__ inline unsigned short f2bf_rne(float f) {
    const unsigned int b = __float_as_uint(f);
    return (unsigned short)((b + 0x7FFFu + ((b >> 16) & 1u)) >> 16);
}
__device__ inline float bf2f(unsigned short h) {
    return __uint_as_float((unsigned int)h << 16);
}

// async 16B global -> LDS (direct-to-shared DMA). LDS dest is wave-uniform
// base; HW writes ldsbase + lane*16. gptr is per-lane.
__device__ inline void async_copy16(const short* g, short* l) {
    __builtin_amdgcn_global_load_lds(
        (const __attribute__((address_space(1))) void*)g,
        (__attribute__((address_space(3))) void*)l, 16, 0, 0);
}

// ---------------------------------------------------------------------------
// Kernel 0: prep — pre-split x and W into FRAGMENT-ORDERED bf16 hi/lo.
// ---------------------------------------------------------------------------
__global__ __launch_bounds__(256) void prep_kernel(
    const float* __restrict__ x,
    const float* __restrict__ Wq, const float* __restrict__ Wk,
    const float* __restrict__ Wv,
    short* __restrict__ xh, short* __restrict__ xl,
    short* __restrict__ wh, short* __restrict__ wl, int BT)
{
    __shared__ float tile[64][69];
    const int tid = threadIdx.x;
    const int bx  = blockIdx.x;
    const int nxb = BT >> 4;

    if (bx < nxb) {
        const int mtg = bx;
        #pragma unroll
        for (int i = 0; i < 8; ++i) {
            const int s    = tid + 256 * i;
            const int kc   = s >> 6;
            const int lane = s & 63;
            const float* src = x + (size_t)(mtg * 16 + (lane & 15)) * D_MODEL
                                 + kc * 32 + (lane >> 4) * 8;
            float v[8];
            *(float4*)&v[0] = *(const float4*)src;
            *(float4*)&v[4] = *(const float4*)(src + 4);
            int4 hi, lo;
            split8(v, hi, lo);
            const size_t off = ((size_t)(mtg * 32 + kc) * 64 + lane) * 8;
            *(int4*)(xh + off) = hi;
            *(int4*)(xl + off) = lo;
        }
    } else {
        const int wb = bx - nxb;
        const int kb = wb & 15;           // k-block 0..15
        const int m  = wb >> 4;           // matrix 0..2
        const float* W = (m == 0) ? Wq : (m == 1) ? Wk : Wv;
        #pragma unroll
        for (int it = 0; it < 4; ++it) {
            const int idx = tid + 256 * it;
            const int kr = idx >> 4, c4 = idx & 15;
            *(float4*)&tile[kr][4 * c4] =
                *(const float4*)(W + (size_t)(kb * 64 + kr) * HS + 4 * c4);
        }
        __syncthreads();
        #pragma unroll
        for (int i = 0; i < 2; ++i) {
            const int s    = tid + 256 * i;    // 0..511
            const int ntl  = s >> 7;           // 0..3
            const int kcl  = (s >> 6) & 1;
            const int lane = s & 63;
            const int n    = ntl * 16 + (lane & 15);
            const int krel = kcl * 32 + (lane >> 4) * 8;
            float v[8];
            #pragma unroll
            for (int e = 0; e < 8; ++e) v[e] = tile[krel + e][n];
            int4 hi, lo;
            split8(v, hi, lo);
            const size_t off =
                ((size_t)((m * 4 + ntl) * 32 + kb * 2 + kcl) * 64 + lane) * 8;
            *(int4*)(wh + off) = hi;
            *(int4*)(wl + off) = lo;
        }
    }
}

// ---------------------------------------------------------------------------
// Kernel 1: QKV projection (async staging; fragment-ordered outputs).
// Grid (BT/32, 3) — round-18 dispatch order (r19's (3, BT/32) swap regressed).
// ---------------------------------------------------------------------------
__global__ __launch_bounds__(256) void qkv_kernel(
    const short* __restrict__ xh, const short* __restrict__ xl,
    const short* __restrict__ wh, const short* __restrict__ wl,
    const float* __restrict__ bq, const float* __restrict__ bk,
    short* __restrict__ qfh, short* __restrict__ qfl,
    short* __restrict__ kfh, short* __restrict__ kfl, short* __restrict__ vf,
    int BT)
{
    __shared__ __align__(16) short A_lds[8 * 512];
    __shared__ __align__(16) short B_lds[16 * 512];

    const int tid  = threadIdx.x;
    const int r0   = blockIdx.x * 32;
    const int nb   = blockIdx.y;
    const int wave = tid >> 6;
    const int lane = tid & 63;
    const int mt_w = wave >> 1;
    const int nt0  = (wave & 1) * 2;

    f32x4 acc0 = (f32x4)(0.f);
    f32x4 acc1 = (f32x4)(0.f);

    const size_t mtg0 = (size_t)(r0 >> 4);
    const size_t ntg0 = (size_t)(nb * 4);

    for (int k0 = 0; k0 < D_MODEL; k0 += 64) {
        const int kc0 = k0 >> 5;
        __syncthreads();
        #pragma unroll
        for (int ii = 0; ii < 6; ++ii) {
            const int g = wave * 6 + ii;
            if (g < 8) {
                const int mt = g >> 2, kcl = (g >> 1) & 1, p = g & 1;
                const short* base = p ? xl : xh;
                const short* gsrc = base + ((mtg0 + mt) * 32 + kc0 + kcl) * 512;
                async_copy16(gsrc + lane * 8, &A_lds[g * 512]);
            } else {
                const int gb = g - 8;
                const int nt = gb >> 2, kcl = (gb >> 1) & 1, p = gb & 1;
                const short* base = p ? wl : wh;
                const short* gsrc = base + ((ntg0 + nt) * 32 + kc0 + kcl) * 512;
                async_copy16(gsrc + lane * 8, &B_lds[gb * 512]);
            }
        }
        __syncthreads();
        #pragma unroll
        for (int kcl = 0; kcl < 2; ++kcl) {
            const bf16x8 afh = *(const bf16x8*)&A_lds[(mt_w * 4 + kcl * 2 + 0) * 512 + lane * 8];
            const bf16x8 afl = *(const bf16x8*)&A_lds[(mt_w * 4 + kcl * 2 + 1) * 512 + lane * 8];
            {
                const bf16x8 bfh = *(const bf16x8*)&B_lds[(nt0 * 4 + kcl * 2 + 0) * 512 + lane * 8];
                const bf16x8 bfl = *(const bf16x8*)&B_lds[(nt0 * 4 + kcl * 2 + 1) * 512 + lane * 8];
                acc0 = __builtin_amdgcn_mfma_f32_16x16x32_bf16(afh, bfh, acc0, 0, 0, 0);
                acc0 = __builtin_amdgcn_mfma_f32_16x16x32_bf16(afh, bfl, acc0, 0, 0, 0);
                acc0 = __builtin_amdgcn_mfma_f32_16x16x32_bf16(afl, bfh, acc0, 0, 0, 0);
            }
            {
                const bf16x8 bfh = *(const bf16x8*)&B_lds[((nt0 + 1) * 4 + kcl * 2 + 0) * 512 + lane * 8];
                const bf16x8 bfl = *(const bf16x8*)&B_lds[((nt0 + 1) * 4 + kcl * 2 + 1) * 512 + lane * 8];
                acc1 = __builtin_amdgcn_mfma_f32_16x16x32_bf16(afh, bfh, acc1, 0, 0, 0);
                acc1 = __builtin_amdgcn_mfma_f32_16x16x32_bf16(afh, bfl, acc1, 0, 0, 0);
                acc1 = __builtin_amdgcn_mfma_f32_16x16x32_bf16(afl, bfh, acc1, 0, 0, 0);
            }
        }
    }

    // ---- epilogue: C/D layout col=lane&15, row=(lane>>4)*4+reg
    const int rowb = r0 + mt_w * 16 + (lane >> 4) * 4;
    #pragma unroll
    for (int j = 0; j < 2; ++j) {
        const f32x4 a = (j == 0) ? acc0 : acc1;
        const int c = nb * 64 + (nt0 + j) * 16 + (lane & 15);
        if (c < 128) {
            // q/k -> fragment-ordered split bf16
            const int cc    = (c < 64) ? c : (c - 64);
            const float bias = (c < 64) ? bq[cc] : bk[cc];
            short* dsth = (c < 64) ? qfh : kfh;
            short* dstl = (c < 64) ? qfl : kfl;
            const int tile16 = rowb >> 4;
            const int kc2   = cc >> 5;
            const int quadd = (cc & 31) >> 3;
            const int e     = cc & 7;
            #pragma unroll
            for (int r = 0; r < 4; ++r) {
                const float val = a[r] + bias;
                const unsigned int b = __float_as_uint(val);
                const unsigned short h = (unsigned short)(b >> 16);
                const float res = val - __uint_as_float((unsigned int)h << 16);
                const unsigned short l16 = (unsigned short)(__float_as_uint(res) >> 16);
                const int laned = ((rowb + r) & 15) | (quadd << 4);
                const size_t off = ((size_t)((tile16 * 2 + kc2) * 64 + laned)) * 8 + e;
                dsth[off] = (short)h;
                dstl[off] = (short)l16;
            }
        } else {
            // v -> fragment-ordered RNE bf16 (vf); 4 consecutive e -> 8B store
            const int cv    = c - 128;
            const int vb    = rowb >> 6;
            const int jc2   = (rowb & 63) >> 5;
            const int quadd = (rowb & 31) >> 3;
            const int gg    = jc2 * 4 + (cv >> 4);
            const int laned = (cv & 15) | (quadd << 4);
            const size_t base = ((size_t)((vb * 8 + gg) * 64 + laned)) * 8 + (rowb & 7);
            short4 pk;
            pk.x = (short)f2bf_rne(a[0]);
            pk.y = (short)f2bf_rne(a[1]);
            pk.z = (short)f2bf_rne(a[2]);
            pk.w = (short)f2bf_rne(a[3]);
            *(short4*)(vf + base) = pk;
        }
    }
}

// ---------------------------------------------------------------------------
// Kernel 2: flash attention via MFMA, async staging.
// ---------------------------------------------------------------------------
__global__ __launch_bounds__(256) void attn_kernel(
    const short* __restrict__ qfh, const short* __restrict__ qfl,
    const short* __restrict__ kfh, const short* __restrict__ kfl,
    const short* __restrict__ vf, const int* __restrict__ maskp,
    float* __restrict__ part_O, float* __restrict__ part_ml, int BT)
{
    __shared__ __align__(16) short Kh[4096], Kl[4096];
    __shared__ __align__(16) short Vt[4096];
    __shared__ __align__(16) short Pl[4][16 * 72];

    const int tile  = blockIdx.x;
    const int chunk = blockIdx.y;
    const int r0 = tile * 64;
    const int tb = r0 / T_LEN;
    const int t0 = r0 - tb * T_LEN;
    const int mask = (*maskp != 0);
    const int n_max = mask ? (t0 + 64) : T_LEN;
    const int j0 = chunk * JCH;
    if (j0 >= n_max) return;
    const int hi_j = min(j0 + JCH, n_max);
    const int njt = (hi_j - j0 + 63) >> 6;

    const int tid  = threadIdx.x;
    const int w    = tid >> 6;
    const int lane = tid & 63;
    const int quad = lane >> 4;
    const int l15  = lane & 15;
    const int rw0  = t0 + 16 * w;
    const int rowa = r0 + 16 * w + quad * 4;

    // Q fragments: direct 16B loads from fragment-ordered split buffers
    bf16x8 qh[2], ql[2];
    {
        const size_t qt = (size_t)(r0 >> 4) + w;
        #pragma unroll
        for (int kc = 0; kc < 2; ++kc) {
            qh[kc] = *(const bf16x8*)&qfh[((qt * 2 + kc) * 64 + lane) * 8];
            ql[kc] = *(const bf16x8*)&qfl[((qt * 2 + kc) * 64 + lane) * 8];
        }
    }

    f32x4 oacc[4];
    #pragma unroll
    for (int nt = 0; nt < 4; ++nt) oacc[nt] = (f32x4)(0.f);
    float m_r[4] = {-INFINITY, -INFINITY, -INFINITY, -INFINITY};
    float l_r[4] = {0.f, 0.f, 0.f, 0.f};

    for (int jt = 0; jt < njt; ++jt) {
        const int jbase = j0 + jt * 64;
        __syncthreads();
        {
            const size_t kt0 = (size_t)(tb * 128) + (jbase >> 4);
            const size_t vb  = (size_t)(tb * 32) + (jbase >> 6);
            #pragma unroll
            for (int ii = 0; ii < 6; ++ii) {
                const int g = w * 6 + ii;       // 0..23
                if (g < 8) {
                    const short* src = kfh + ((kt0 + (g >> 1)) * 2 + (g & 1)) * 512;
                    async_copy16(src + lane * 8, &Kh[g * 512]);
                } else if (g < 16) {
                    const int gg = g - 8;
                    const short* src = kfl + ((kt0 + (gg >> 1)) * 2 + (gg & 1)) * 512;
                    async_copy16(src + lane * 8, &Kl[gg * 512]);
                } else {
                    const int gg = g - 16;
                    const short* src = vf + (vb * 8 + gg) * 512;
                    async_copy16(src + lane * 8, &Vt[gg * 512]);
                }
            }
        }
        __syncthreads();

        const bool active = (!mask) || (jbase <= rw0 + 15);
        if (active) {
            f32x4 sacc[4];
            #pragma unroll
            for (int jsub = 0; jsub < 4; ++jsub) {
                f32x4 s = (f32x4)(0.f);
                #pragma unroll
                for (int kc = 0; kc < 2; ++kc) {
                    const bf16x8 kh = *(const bf16x8*)&Kh[((jsub * 2 + kc) * 64 + lane) * 8];
                    const bf16x8 kl = *(const bf16x8*)&Kl[((jsub * 2 + kc) * 64 + lane) * 8];
                    s = __builtin_amdgcn_mfma_f32_16x16x32_bf16(qh[kc], kh, s, 0, 0, 0);
                    s = __builtin_amdgcn_mfma_f32_16x16x32_bf16(qh[kc], kl, s, 0, 0, 0);
                    s = __builtin_amdgcn_mfma_f32_16x16x32_bf16(ql[kc], kh, s, 0, 0, 0);
                }
                sacc[jsub] = s;
            }
            float sval[4][4], rmax[4];
            #pragma unroll
            for (int r = 0; r < 4; ++r) rmax[r] = -INFINITY;
            #pragma unroll
            for (int jsub = 0; jsub < 4; ++jsub) {
                const int jg = jbase + jsub * 16 + l15;
                #pragma unroll
                for (int r = 0; r < 4; ++r) {
                    const int tg = rw0 + quad * 4 + r;
                    const float vv = (mask && (jg > tg)) ? -INFINITY : 8.0f * sacc[jsub][r];
                    sval[jsub][r] = vv;
                    rmax[r] = fmaxf(rmax[r], vv);
                }
            }
            #pragma unroll
            for (int d = 1; d < 16; d <<= 1)
                #pragma unroll
                for (int r = 0; r < 4; ++r)
                    rmax[r] = fmaxf(rmax[r], __shfl_xor(rmax[r], d));
            float alpha[4], msafe[4];
            #pragma unroll
            for (int r = 0; r < 4; ++r) {
                const float mn = fmaxf(m_r[r], rmax[r]);
                msafe[r] = (mn == -INFINITY) ? 0.f : mn;
                alpha[r] = __expf(m_r[r] - msafe[r]);
                m_r[r] = mn;
            }
            short* Pw = &Pl[w][0];
            float rsum[4] = {0.f, 0.f, 0.f, 0.f};
            #pragma unroll
            for (int jsub = 0; jsub < 4; ++jsub) {
                #pragma unroll
                for (int r = 0; r < 4; ++r) {
                    const float e = __expf(sval[jsub][r] - msafe[r]);
                    const unsigned short eb = f2bf_rne(e);
                    Pw[(quad * 4 + r) * 72 + jsub * 16 + l15] = (short)eb;
                    rsum[r] += bf2f(eb);
                }
            }
            #pragma unroll
            for (int d = 1; d < 16; d <<= 1)
                #pragma unroll
                for (int r = 0; r < 4; ++r)
                    rsum[r] += __shfl_xor(rsum[r], d);
            #pragma unroll
            for (int r = 0; r < 4; ++r)
                l_r[r] = l_r[r] * alpha[r] + rsum[r];
            #pragma unroll
            for (int nt = 0; nt < 4; ++nt)
                #pragma unroll
                for (int r = 0; r < 4; ++r)
                    oacc[nt][r] *= alpha[r];
            bf16x8 pf[2];
            #pragma unroll
            for (int jc = 0; jc < 2; ++jc)
                pf[jc] = *(const bf16x8*)&Pw[l15 * 72 + jc * 32 + quad * 8];
            #pragma unroll
            for (int nt = 0; nt < 4; ++nt) {
                #pragma unroll
                for (int jc = 0; jc < 2; ++jc) {
                    const bf16x8 vfr = *(const bf16x8*)&Vt[((jc * 4 + nt) * 64 + lane) * 8];
                    oacc[nt] = __builtin_amdgcn_mfma_f32_16x16x32_bf16(pf[jc], vfr, oacc[nt], 0, 0, 0);
                }
            }
        }
    }

    #pragma unroll
    for (int nt = 0; nt < 4; ++nt)
        #pragma unroll
        for (int r = 0; r < 4; ++r)
            part_O[((size_t)(rowa + r) * NCH + chunk) * HS + nt * 16 + l15] = oacc[nt][r];
    if (l15 == 0) {
        #pragma unroll
        for (int r = 0; r < 4; ++r) {
            float2 ml;
            ml.x = m_r[r];
            ml.y = l_r[r];
            *(float2*)(part_ml + ((size_t)(rowa + r) * NCH + chunk) * 2) = ml;
        }
    }
}

// ---------------------------------------------------------------------------
// Kernel 3: combine chunk partials — vectorized (1 thread per row x 4 dims).
// ---------------------------------------------------------------------------
__global__ __launch_bounds__(256) void combine_kernel(
    const float* __restrict__ part_O, const float* __restrict__ part_ml,
    const int* __restrict__ maskp, float* __restrict__ out)
{
    const int f = blockIdx.x * 256 + threadIdx.x;   // BT*16 threads total
    const int row = f >> 4;
    const int d4 = (f & 15) * 4;
    const int t = row & (T_LEN - 1);
    const int mask = (*maskp != 0);
    const int n = mask ? (t + 1) : T_LEN;
    const int nc = (n + JCH - 1) / JCH;

    const float2* mlp = (const float2*)(part_ml + (size_t)row * NCH * 2);
    float M = -INFINITY;
    for (int c = 0; c < nc; ++c) M = fmaxf(M, mlp[c].x);
    float L = 0.f;
    float Ox = 0.f, Oy = 0.f, Oz = 0.f, Ow = 0.f;
    for (int c = 0; c < nc; ++c) {
        const float2 ml = mlp[c];
        const float w = __expf(ml.x - M);
        L += ml.y * w;
        const float4 p = *(const float4*)(part_O + ((size_t)row * NCH + c) * HS + d4);
        Ox = fmaf(p.x, w, Ox);
        Oy = fmaf(p.y, w, Oy);
        Oz = fmaf(p.z, w, Oz);
        Ow = fmaf(p.w, w, Ow);
    }
    float4 res;
    res.x = Ox / L;
    res.y = Oy / L;
    res.z = Oz / L;
    res.w = Ow / L;
    *(float4*)(out + (size_t)row * HS + d4) = res;
}

// ---------------------------------------------------------------------------
extern "C" void kernel_launch(void* const* d_in, const int* in_sizes, int n_in,
                              void* d_out, int out_size, void* d_ws, size_t ws_size,
                              hipStream_t stream) {
    const float* x  = (const float*)d_in[0];
    const float* Wq = (const float*)d_in[1];
    const float* bq = (const float*)d_in[2];
    const float* Wk = (const float*)d_in[3];
    const float* bk = (const float*)d_in[4];
    const float* Wv = (const float*)d_in[5];
    const int* maskp = (const int*)d_in[6];

    const int BT = in_sizes[0] / D_MODEL;   // 8192

    // ws layout: floats pO [BT*NCH*64], pml [BT*NCH*2]; shorts xh,xl
    // [BT*1024], wh,wl [192*1024], qfh,qfl,kfh,kfl,vf [BT*64].
    float* pO  = (float*)d_ws;
    float* pml = pO + (size_t)BT * NCH * HS;
    short* xh  = (short*)(pml + (size_t)BT * NCH * 2);
    short* xl  = xh + (size_t)BT * D_MODEL;
    short* wh  = xl + (size_t)BT * D_MODEL;
    short* wl  = wh + (size_t)192 * D_MODEL;
    short* qfh = wl + (size_t)192 * D_MODEL;
    short* qfl = qfh + (size_t)BT * HS;
    short* kfh = qfl + (size_t)BT * HS;
    short* kfl = kfh + (size_t)BT * HS;
    short* vf  = kfl + (size_t)BT * HS;

    prep_kernel<<<BT / 16 + 48, 256, 0, stream>>>(x, Wq, Wk, Wv, xh, xl, wh, wl, BT);
    dim3 qgrid(BT / 32, 3);
    qkv_kernel<<<qgrid, 256, 0, stream>>>(xh, xl, wh, wl, bq, bk,
                                          qfh, qfl, kfh, kfl, vf, BT);
    dim3 agrid(BT / 64, NCH);
    attn_kernel<<<agrid, 256, 0, stream>>>(qfh, qfl, kfh, kfl, vf, maskp,
                                           pO, pml, BT);
    combine_kernel<<<(BT * 16) / 256, 256, 0, stream>>>(pO, pml, maskp, (float*)d_out);
}